// Round 11
// baseline (63.991 us; speedup 1.0000x reference)
//
#include <hip/hip_runtime.h>
#include <hip/hip_bf16.h>
#include <math.h>

// out[n,:] = s1 .* FWHT( (u/4096) .* FWHT( s2 .* x[n,:] ) ),
// u = g_mu + softplus(g_rho)*epsilon, FWHT = unnormalized Walsh-Hadamard.
//
// R11 = R10 (f2 row-pair x radix-64x64, 2 LDS transposes, quad-DPP H64)
// with ONE change: the LDS cell map now spreads banks at QUAD granularity.
// R10's map had every quad (4 lanes differing only in q) hitting one
// bank-group at 4 rows on all four patterns -> SQ_LDS_BANK_CONFLICT 9.96M.
// New map: element (line, g) stored at f2-addr
//   line*64 + 2*mu + (g&1),  P = g>>1,
//   mu = (P&24) | ((P&7) ^ (P>>3) ^ tau(line)),
//   tau(line) = (line&7) ^ ((line>>4)&3)
// Hand-checked: b128 write/read quad -> 4 distinct 4-bank groups (q enters
// via P>>3); b64 read/write quad -> 4 distinct bank-pairs (q enters via
// tau(16q+r)); full-wave distributions at the data-volume minimum.
// Bijective per line; preserves f2-pair adjacency + 16B alignment; same
// thread-local read/write sets as R10 -> same 2-barrier hazard structure.

#define WHVI_D 4096

typedef float f2 __attribute__((ext_vector_type(2)));

__global__ __launch_bounds__(256)
void u_precompute_kernel(const float* __restrict__ g_mu,
                         const float* __restrict__ g_rho,
                         const float* __restrict__ g_eps,
                         float* __restrict__ u_perm) {
    int k = blockIdx.x * 256 + threadIdx.x;  // 0..4095, coalesced
    float rho = g_rho[k];
    float sp = fmaxf(rho, 0.0f) + __logf(1.0f + __expf(-fabsf(rho)));
    float uu = (g_mu[k] + sp * g_eps[k]) * (1.0f / 4096.0f);
    // At diag time thread t holds element (h = 16*(t&3) + r, g = t>>2),
    // i.e. i = 64h + g. Invert: store u[i] at u_perm[(4g + q)*16 + r].
    int h = k >> 6, g = k & 63;
    int q = (h >> 4) & 3, r = h & 15;
    u_perm[(4 * g + q) * 16 + r] = uu;
}

template <int CTRL>
__device__ __forceinline__ float dppf(float x) {
    return __builtin_bit_cast(float,
        __builtin_amdgcn_mov_dpp(__builtin_bit_cast(int, x), CTRL, 0xF, 0xF, false));
}

// one cross-lane butterfly level: v' = sgn*v + partner  (R9/R10-verified)
template <int CTRL>
__device__ __forceinline__ void dpp_level(f2 v[16], float sgn) {
#pragma unroll
    for (int k = 0; k < 16; ++k) {
        float px = dppf<CTRL>(v[k].x);
        float py = dppf<CTRL>(v[k].y);
        v[k].x = fmaf(sgn, v[k].x, px);
        v[k].y = fmaf(sgn, v[k].y, py);
    }
}

// H64 over one 6-bit digit: bits 0-3 in regs (pk), bit4 = lane^1, bit5 = lane^2.
__device__ __forceinline__ void h64(f2 v[16], float sA, float sB) {
#pragma unroll
    for (int s = 1; s < 16; s <<= 1) {
#pragma unroll
        for (int i = 0; i < 16; ++i) {
            if ((i & s) == 0) {
                f2 a = v[i], b = v[i | s];
                v[i] = a + b;       // v_pk_add_f32
                v[i | s] = a - b;
            }
        }
    }
    dpp_level<0xB1>(v, sA);  // quad_perm [1,0,3,2] : lane^1
    dpp_level<0x4E>(v, sB);  // quad_perm [2,3,0,1] : lane^2
}

// f2-index of the cell holding element (line, g). See header comment.
__device__ __forceinline__ int cell_addr(int line, int g) {
    int P = g >> 1;
    int tau = (line & 7) ^ ((line >> 4) & 3);
    int mu = (P & 24) | ((P & 7) ^ (P >> 3) ^ tau);
    return line * 64 + 2 * mu + (g & 1);
}

__global__ __launch_bounds__(256)
void whvi64p_kernel(const float* __restrict__ x,
                    const float* __restrict__ s1,
                    const float* __restrict__ s2,
                    const float* __restrict__ u_perm,
                    float* __restrict__ out,
                    int nrows) {
    __shared__ __align__(16) f2 lds[WHVI_D];  // 32 KB

    const int t = threadIdx.x;     // 0..255
    const int q = t & 3;           // quarter (lane bits 0-1)
    const int h = t >> 2;          // owned h-line (phase A) / g-line (phase B)
    const float sA = (t & 1) ? -1.0f : 1.0f;   // digit bit4 sign
    const float sB = (t & 2) ? -1.0f : 1.0f;   // digit bit5 sign

    const int r0 = blockIdx.x * 2;
    const bool r1_valid = (r0 + 1 < nrows);
    const size_t base0 = (size_t)r0 * WHVI_D;
    const size_t base1 = (size_t)(r0 + (r1_valid ? 1 : 0)) * WHVI_D;

    f2 v[16];

    // ---- load row pair + s2, pack (b128, i = 16t + j) ----
    {
        const float4* xa = reinterpret_cast<const float4*>(x + base0 + t * 16);
        const float4* xb = reinterpret_cast<const float4*>(x + base1 + t * 16);
        const float4* sv = reinterpret_cast<const float4*>(s2 + t * 16);
#pragma unroll
        for (int c = 0; c < 4; ++c) {
            float4 a = xa[c], b = xb[c], s = sv[c];
            v[4 * c + 0] = f2{a.x * s.x, b.x * s.x};
            v[4 * c + 1] = f2{a.y * s.y, b.y * s.y};
            v[4 * c + 2] = f2{a.z * s.z, b.z * s.z};
            v[4 * c + 3] = f2{a.w * s.w, b.w * s.w};
        }
    }

    // ---- FWHT#1 g-side: H64 over g (regs j = g bits 0-3; q = bits 4-5) ----
    h64(v, sA, sB);

    // issue u_perm loads early (first use ~2 h64's later)
    const float4* upv = reinterpret_cast<const float4*>(u_perm + t * 16);
    float4 upr[4];
#pragma unroll
    for (int c = 0; c < 4; ++c) upr[c] = upv[c];

    // ---- T1: write (h, g=16q+2c..+1) b128; bar; read (16q+r, h) b64 ----
#pragma unroll
    for (int c = 0; c < 8; ++c) {
        int a0 = cell_addr(h, 16 * q + 2 * c);  // even g -> even addr, 16B ok
        *reinterpret_cast<float4*>(&lds[a0]) =
            make_float4(v[2 * c].x, v[2 * c].y, v[2 * c + 1].x, v[2 * c + 1].y);
    }
    __syncthreads();
#pragma unroll
    for (int r = 0; r < 16; ++r)
        v[r] = lds[cell_addr(16 * q + r, h)];

    // ---- FWHT#1 h-side: H64 over h ----
    h64(v, sA, sB);

    // ---- diagonal u (1/4096 folded), per-thread-contiguous b128 ----
#pragma unroll
    for (int c = 0; c < 4; ++c) {
        v[4 * c + 0] *= upr[c].x;
        v[4 * c + 1] *= upr[c].y;
        v[4 * c + 2] *= upr[c].z;
        v[4 * c + 3] *= upr[c].w;
    }

    // ---- FWHT#2 h-side (h digits still in regs/lanes) ----
    h64(v, sA, sB);

    // issue s1 loads (first use after T2 + h64)
    const float4* s1v = reinterpret_cast<const float4*>(s1 + t * 16);
    float4 s1r[4];
#pragma unroll
    for (int c = 0; c < 4; ++c) s1r[c] = s1v[c];

    // ---- T2: write back same addrs as T1-read (same-thread, FIFO-safe);
    //      bar; read b128 rows (= T1-write addrs) ----
#pragma unroll
    for (int r = 0; r < 16; ++r)
        lds[cell_addr(16 * q + r, h)] = v[r];
    __syncthreads();
#pragma unroll
    for (int c = 0; c < 8; ++c) {
        int a0 = cell_addr(h, 16 * q + 2 * c);
        float4 tt = *reinterpret_cast<const float4*>(&lds[a0]);
        v[2 * c]     = f2{tt.x, tt.y};
        v[2 * c + 1] = f2{tt.z, tt.w};
    }

    // ---- FWHT#2 g-side -> natural order: v[j] = out-element 16t + j ----
    h64(v, sA, sB);

    // ---- s1 scale + store both rows (b128) ----
    {
        float4* o0 = reinterpret_cast<float4*>(out + base0 + t * 16);
        float4* o1 = reinterpret_cast<float4*>(out + base1 + t * 16);
#pragma unroll
        for (int c = 0; c < 4; ++c) {
            float4 s = s1r[c];
            o0[c] = make_float4(v[4 * c + 0].x * s.x, v[4 * c + 1].x * s.y,
                                v[4 * c + 2].x * s.z, v[4 * c + 3].x * s.w);
            if (r1_valid)
                o1[c] = make_float4(v[4 * c + 0].y * s.x, v[4 * c + 1].y * s.y,
                                    v[4 * c + 2].y * s.z, v[4 * c + 3].y * s.w);
        }
    }
}

extern "C" void kernel_launch(void* const* d_in, const int* in_sizes, int n_in,
                              void* d_out, int out_size, void* d_ws, size_t ws_size,
                              hipStream_t stream) {
    const float* x     = (const float*)d_in[0];
    const float* s1    = (const float*)d_in[1];
    const float* s2    = (const float*)d_in[2];
    const float* g_mu  = (const float*)d_in[3];
    const float* g_rho = (const float*)d_in[4];
    const float* g_eps = (const float*)d_in[5];
    // d_in[6] is H — unused; the FWHT realizes it exactly.
    float* out = (float*)d_out;

    const int nrows = in_sizes[0] / WHVI_D;  // 8192

    float* u_perm = (float*)d_ws;  // 16 KB of workspace
    u_precompute_kernel<<<WHVI_D / 256, 256, 0, stream>>>(g_mu, g_rho, g_eps, u_perm);

    const int npairs = (nrows + 1) / 2;
    whvi64p_kernel<<<npairs, 256, 0, stream>>>(x, s1, s2, u_perm, out, nrows);
}